// Round 6
// baseline (1805.252 us; speedup 1.0000x reference)
//
#include <hip/hip_runtime.h>
#include <hip/hip_bf16.h>
#include <stdint.h>

#define BTOT  65536
#define KTR   11
#define NSLOT 12   // 11 transforms + z

typedef __attribute__((ext_vector_type(8))) short bf16x8_t;
typedef __attribute__((ext_vector_type(4))) float f32x4_t;

// Swizzled LDS layout: row m x 256 bf16 cols, 16B groups rotated by row so
// frag ds_read_b128 across 16 rows spreads banks (<=2-way, free per m136).
__device__ __forceinline__ int act_addr(int m, int n) {
    return m * 256 + ((((n >> 3) + m) & 31) << 3) + (n & 7);
}

// tanh-form gelu; |err| <~1e-3, invisible under bf16 storage noise.
__device__ __forceinline__ float gelu_fast(float x) {
    float x2 = x * x;
    float t2 = 1.5957691216057308f * x * fmaf(0.044715f, x2, 1.0f);
    float e  = __expf(fminf(t2, 30.f));
    return x * e * __builtin_amdgcn_rcpf(1.0f + e);
}

__global__ void zero_counters_kernel(int* __restrict__ cnt, int n) {
    for (int i = threadIdx.x; i < n; i += 256) cnt[i] = 0;
}

__global__ void cast_x_kernel(const float* __restrict__ x, __hip_bfloat16* __restrict__ xb) {
    int i = (blockIdx.x * 256 + threadIdx.x) * 4;
    float4 v = *(const float4*)(x + i);
    union { __hip_bfloat16 h[4]; uint64_t u; } o;
    o.h[0] = __float2bfloat16(v.x);
    o.h[1] = __float2bfloat16(v.y);
    o.h[2] = __float2bfloat16(v.z);
    o.h[3] = __float2bfloat16(v.w);
    *(uint64_t*)(xb + i) = o.u;
}

// out[b][c][r] = in[b][r][c], cast fp32 -> bf16.
__global__ void transpose_cast_kernel(const float* __restrict__ in,
                                      __hip_bfloat16* __restrict__ out,
                                      int R, int C) {
    __shared__ float tile[32][33];
    int tpc = C >> 5;
    int tr = (blockIdx.x / tpc) << 5;
    int tc = (blockIdx.x % tpc) << 5;
    const float* bi = in + (size_t)blockIdx.y * R * C;
    __hip_bfloat16* bo = out + (size_t)blockIdx.y * R * C;
    int lx = threadIdx.x & 31, ly = threadIdx.x >> 5;
    #pragma unroll
    for (int r = 0; r < 32; r += 8)
        tile[ly + r][lx] = bi[(size_t)(tr + ly + r) * C + tc + lx];
    __syncthreads();
    #pragma unroll
    for (int r = 0; r < 32; r += 8)
        bo[(size_t)(tc + ly + r) * R + tr + lx] = __float2bfloat16(tile[lx][ly + r]);
}

// One stage: act[64][256] (LDS, swizzled) <- f(act @ W + bias).
// Operand-swapped MFMA: D = W^T (A-op, global L2-hot) x act^T (B-op, LDS).
// Wave w owns weight-col strip [w*64,+64) x all 64 batch rows.
// Weight prefetch depth 2 (~260 cyc slack, covers L2 hit latency).
__device__ void run_stage(__hip_bfloat16* act,
                          const __hip_bfloat16* __restrict__ Wt,   // [n][k] row-major
                          const float* __restrict__ bias,
                          bool do_gelu, int wave, int lane)
{
    const int lr = lane & 15;
    const int q  = lane >> 4;
    const int wc = wave << 6;           // weight-col strip base

    const __hip_bfloat16* wrow[4];
    #pragma unroll
    for (int mt = 0; mt < 4; ++mt)
        wrow[mt] = Wt + (size_t)(wc + (mt << 4) + lr) * 256 + (q << 3);

    f32x4_t acc[4][4];
    #pragma unroll
    for (int mt = 0; mt < 4; ++mt)
        #pragma unroll
        for (int nt = 0; nt < 4; ++nt)
            acc[mt][nt] = (f32x4_t){0.f, 0.f, 0.f, 0.f};

    // prefetch A-frags (weights) for kc=0,1
    bf16x8_t a0[4], a1[4];
    #pragma unroll
    for (int mt = 0; mt < 4; ++mt) a0[mt] = *(const bf16x8_t*)(wrow[mt]);
    #pragma unroll
    for (int mt = 0; mt < 4; ++mt) a1[mt] = *(const bf16x8_t*)(wrow[mt] + 32);

    #pragma unroll 1
    for (int kc = 0; kc < 8; ++kc) {
        const int kof = (kc << 5) + (q << 3);
        bf16x8_t an[4];
        if (kc < 6) {
            #pragma unroll
            for (int mt = 0; mt < 4; ++mt)
                an[mt] = *(const bf16x8_t*)(wrow[mt] + ((kc + 2) << 5));
        }
        bf16x8_t b[4];
        #pragma unroll
        for (int nt = 0; nt < 4; ++nt)
            b[nt] = *(const bf16x8_t*)(act + act_addr((nt << 4) + lr, kof));
        #pragma unroll
        for (int mt = 0; mt < 4; ++mt)
            #pragma unroll
            for (int nt = 0; nt < 4; ++nt)
                acc[mt][nt] = __builtin_amdgcn_mfma_f32_16x16x32_bf16(a0[mt], b[nt], acc[mt][nt], 0, 0, 0);
        #pragma unroll
        for (int mt = 0; mt < 4; ++mt) { a0[mt] = a1[mt]; a1[mt] = an[mt]; }
    }

    __syncthreads();   // all waves done reading act before overwrite
    #pragma unroll
    for (int mt = 0; mt < 4; ++mt) {
        const int nbase = wc + (mt << 4) + (q << 2);
        const float4 bv = *(const float4*)(bias + nbase);
        #pragma unroll
        for (int nt = 0; nt < 4; ++nt) {
            const int row = (nt << 4) + lr;
            union { __hip_bfloat16 h[4]; uint64_t u; } o;
            #pragma unroll
            for (int r = 0; r < 4; ++r) {
                float v = acc[mt][nt][r] + ((const float*)&bv)[r];
                if (do_gelu) v = gelu_fast(v);
                o.h[r] = __float2bfloat16(v);
            }
            *(uint64_t*)(act + act_addr(row, nbase)) = o.u;
        }
    }
    __syncthreads();
}

// Fused chain + per-tile reduce. Grid (slot=12, tile): same-tile blocks are
// dispatch-adjacent so their zbuf writes are L2/L3-hot when the 12th arriver
// (atomic ticket) reduces the tile in-place. No separate reduce dispatch.
__launch_bounds__(256, 3)
__global__ void chain_kernel(const __hip_bfloat16* __restrict__ xb,
                             const __hip_bfloat16* __restrict__ Tw1t,
                             const float* __restrict__ Tb1,
                             const __hip_bfloat16* __restrict__ Tw2t,
                             const float* __restrict__ Tb2,
                             const __hip_bfloat16* __restrict__ Ew1t,
                             const float* __restrict__ Eb1,
                             const __hip_bfloat16* __restrict__ Ew2t,
                             const float* __restrict__ Eb2,
                             __hip_bfloat16* __restrict__ zbuf,
                             int* __restrict__ counters,
                             float* __restrict__ out,
                             int b0)
{
    __shared__ __align__(16) __hip_bfloat16 act[64 * 256];   // 32 KB
    __shared__ float Gw[4][16][17];
    __shared__ int is_last;
    const int tid  = threadIdx.x;
    const int wave = tid >> 6, lane = tid & 63;
    const int slot = blockIdx.x;   // 0..11
    const int tile = blockIdx.y;

    // stage x tile (64 rows) into LDS
    #pragma unroll
    for (int i = 0; i < 8; ++i) {
        int lin = i * 256 + tid;
        int r = lin >> 5, g = lin & 31;
        bf16x8_t v = *(const bf16x8_t*)(xb + (size_t)(b0 + tile * 64 + r) * 256 + g * 8);
        *(bf16x8_t*)(act + act_addr(r, g * 8)) = v;
    }
    __syncthreads();

    if (slot < KTR) {
        run_stage(act, Tw1t + (size_t)slot * 65536, Tb1 + slot * 256, true,  wave, lane);
        run_stage(act, Tw2t + (size_t)slot * 65536, Tb2 + slot * 256, false, wave, lane);
    }
    run_stage(act, Ew1t, Eb1, true,  wave, lane);
    run_stage(act, Ew2t, Eb2, false, wave, lane);

    // write z tile to interleaved zbuf: [row][slot][256]
    __hip_bfloat16* dst = zbuf + ((size_t)(tile * 64) * NSLOT + slot) * 256;
    #pragma unroll
    for (int i = 0; i < 8; ++i) {
        int lin = i * 256 + tid;
        int r = lin >> 5, g = lin & 31;
        bf16x8_t v = *(const bf16x8_t*)(act + act_addr(r, g * 8));
        *(bf16x8_t*)(dst + (size_t)r * NSLOT * 256 + g * 8) = v;
    }

    // ---- atomic ticket: 12th arriver reduces this tile ----
    __syncthreads();   // barrier drains all waves' stores (vmcnt 0 before s_barrier)
    if (tid == 0) {
        int old = __hip_atomic_fetch_add(&counters[tile], 1,
                                         __ATOMIC_ACQ_REL, __HIP_MEMORY_SCOPE_AGENT);
        is_last = (old == NSLOT - 1);
    }
    __syncthreads();
    if (!is_last) return;
    // device-scope acquire: invalidate stale L1/L2 lines before reading other
    // blocks' zbuf writes (cross-XCD per G16)
    __builtin_amdgcn_fence(__ATOMIC_ACQUIRE, "agent");

    // reduce 64 rows, 4 per round: stage 4 rows x 12 slots (24 KB) into act,
    // wave w computes row g*4+w via the 12-slot Gram MFMA trick (R4-verified).
    const int lr = lane & 15, q = lane >> 4;
    const int zslot = lr < NSLOT ? lr : NSLOT - 1;
    #pragma unroll 1
    for (int g = 0; g < 16; ++g) {
        const size_t src = ((size_t)(tile * 64 + g * 4)) * (NSLOT * 256);
        __syncthreads();   // previous round's reads done before overwrite
        #pragma unroll
        for (int i = 0; i < 6; ++i) {
            int e = (i * 256 + tid) * 8;
            bf16x8_t v = *(const bf16x8_t*)(zbuf + src + e);
            *(bf16x8_t*)(act + act_addr(e >> 8, e & 255)) = v;
        }
        __syncthreads();

        const int rs0 = wave * NSLOT;
        f32x4_t acc = (f32x4_t){0.f, 0.f, 0.f, 0.f};
        #pragma unroll
        for (int kc = 0; kc < 8; ++kc) {
            bf16x8_t v = *(const bf16x8_t*)(act + act_addr(rs0 + zslot, kc * 32 + q * 8));
            acc = __builtin_amdgcn_mfma_f32_16x16x32_bf16(v, v, acc, 0, 0, 0);
        }
        #pragma unroll
        for (int r = 0; r < 4; ++r)
            Gw[wave][(q << 2) + r][lr] = acc[r];
        // wave-local RAW on Gw: lgkmcnt orders it; no block barrier needed
        float term = 0.f;
        if (lane < 11) {
            const int k = lane;
            float n[NSLOT];
            #pragma unroll
            for (int l = 0; l < NSLOT; ++l) n[l] = sqrtf(Gw[wave][l][l]);
            const float nk = n[k];
            float neg = 0.f;
            #pragma unroll
            for (int l = 0; l < KTR; ++l)
                if (l != k)
                    neg += __expf(Gw[wave][l][k] / fmaxf(n[l] * nk, 1e-8f));
            float cz = Gw[wave][KTR][k] / fmaxf(n[KTR] * nk, 1e-8f);
            term = __logf(__expf(cz) + neg) - cz;
        }
        term += __shfl_xor(term, 1);
        term += __shfl_xor(term, 2);
        term += __shfl_xor(term, 4);
        term += __shfl_xor(term, 8);
        if (lane == 0) out[b0 + tile * 64 + g * 4 + wave] = term;
    }
}

extern "C" void kernel_launch(void* const* d_in, const int* in_sizes, int n_in,
                              void* d_out, int out_size, void* d_ws, size_t ws_size,
                              hipStream_t stream)
{
    const float* x   = (const float*)d_in[0];
    const float* Tw1 = (const float*)d_in[1];
    const float* Tb1 = (const float*)d_in[2];
    const float* Tw2 = (const float*)d_in[3];
    const float* Tb2 = (const float*)d_in[4];
    const float* Ew1 = (const float*)d_in[5];
    const float* Eb1 = (const float*)d_in[6];
    const float* Ew2 = (const float*)d_in[7];
    const float* Eb2 = (const float*)d_in[8];
    float* out = (float*)d_out;

    char* ws = (char*)d_ws;
    const size_t off_xb  = 0;
    const size_t off_tw1 = off_xb  + (size_t)BTOT * 256 * 2;   // 32 MB
    const size_t off_tw2 = off_tw1 + (size_t)KTR * 65536 * 2;
    const size_t off_ew1 = off_tw2 + (size_t)KTR * 65536 * 2;
    const size_t off_ew2 = off_ew1 + (size_t)65536 * 2;
    const size_t off_cnt = off_ew2 + (size_t)65536 * 2;
    const size_t off_z   = off_cnt + (size_t)4096 * 4;         // 1024 counters max

    __hip_bfloat16* xb   = (__hip_bfloat16*)(ws + off_xb);
    __hip_bfloat16* Tw1t = (__hip_bfloat16*)(ws + off_tw1);
    __hip_bfloat16* Tw2t = (__hip_bfloat16*)(ws + off_tw2);
    __hip_bfloat16* Ew1t = (__hip_bfloat16*)(ws + off_ew1);
    __hip_bfloat16* Ew2t = (__hip_bfloat16*)(ws + off_ew2);
    int*            cnt  = (int*)(ws + off_cnt);
    __hip_bfloat16* zbuf = (__hip_bfloat16*)(ws + off_z);

    // single pass if scratch allows (~420 MB); chunk only as fallback
    long long zbytes = (long long)ws_size - (long long)off_z;
    long long rows_cap = zbytes > 0 ? zbytes / ((long long)NSLOT * 256 * 2) : 0;
    int chunk = (int)((rows_cap / 128) * 128);
    if (chunk > BTOT) chunk = BTOT;
    if (chunk < 128) chunk = 128;

    cast_x_kernel<<<dim3(BTOT * 256 / 1024), 256, 0, stream>>>(x, xb);
    transpose_cast_kernel<<<dim3(64, KTR), 256, 0, stream>>>(Tw1, Tw1t, 256, 256);
    transpose_cast_kernel<<<dim3(64, KTR), 256, 0, stream>>>(Tw2, Tw2t, 256, 256);
    transpose_cast_kernel<<<dim3(64, 1),   256, 0, stream>>>(Ew1, Ew1t, 256, 256);
    transpose_cast_kernel<<<dim3(64, 1),   256, 0, stream>>>(Ew2, Ew2t, 256, 256);

    for (int b0 = 0; b0 < BTOT; b0 += chunk) {
        int rows = (BTOT - b0 < chunk) ? (BTOT - b0) : chunk;
        zero_counters_kernel<<<1, 256, 0, stream>>>(cnt, rows / 64);
        chain_kernel<<<dim3(NSLOT, rows / 64), 256, 0, stream>>>(
            xb, Tw1t, Tb1, Tw2t, Tb2, Ew1t, Eb1, Ew2t, Eb2, zbuf, cnt, out, b0);
    }
}

// Round 7
// 1040.443 us; speedup vs baseline: 1.7351x; 1.7351x over previous
//
#include <hip/hip_runtime.h>
#include <hip/hip_bf16.h>
#include <stdint.h>

#define BTOT  65536
#define KTR   11
#define NSLOT 12   // 11 transforms + z

typedef __attribute__((ext_vector_type(8))) short bf16x8_t;
typedef __attribute__((ext_vector_type(4))) float f32x4_t;

// Swizzled LDS layout (bf16): row m x 256 cols, 16B groups (8 elems) rotated
// by row so frag ds_read_b128 across 16 rows spreads banks (<=2-way, free).
__device__ __forceinline__ int act_addr(int m, int n) {
    return m * 256 + ((((n >> 3) + m) & 31) << 3) + (n & 7);
}

// Swizzled LDS layout (fp8 bytes): row r x 256 B, 16B groups rotated by row.
__device__ __forceinline__ int z8_addr(int r, int b) {
    return r * 256 + ((((b >> 4) + r) & 15) << 4) + (b & 15);
}

// tanh-form gelu; |err| <~1e-3, invisible under bf16 storage noise.
__device__ __forceinline__ float gelu_fast(float x) {
    float x2 = x * x;
    float t2 = 1.5957691216057308f * x * fmaf(0.044715f, x2, 1.0f);
    float e  = __expf(fminf(t2, 30.f));
    return x * e * __builtin_amdgcn_rcpf(1.0f + e);
}

__global__ void cast_x_kernel(const float* __restrict__ x, __hip_bfloat16* __restrict__ xb) {
    int i = (blockIdx.x * 256 + threadIdx.x) * 4;
    float4 v = *(const float4*)(x + i);
    union { __hip_bfloat16 h[4]; uint64_t u; } o;
    o.h[0] = __float2bfloat16(v.x);
    o.h[1] = __float2bfloat16(v.y);
    o.h[2] = __float2bfloat16(v.z);
    o.h[3] = __float2bfloat16(v.w);
    *(uint64_t*)(xb + i) = o.u;
}

// out[b][c][r] = in[b][r][c], cast fp32 -> bf16.
__global__ void transpose_cast_kernel(const float* __restrict__ in,
                                      __hip_bfloat16* __restrict__ out,
                                      int R, int C) {
    __shared__ float tile[32][33];
    int tpc = C >> 5;
    int tr = (blockIdx.x / tpc) << 5;
    int tc = (blockIdx.x % tpc) << 5;
    const float* bi = in + (size_t)blockIdx.y * R * C;
    __hip_bfloat16* bo = out + (size_t)blockIdx.y * R * C;
    int lx = threadIdx.x & 31, ly = threadIdx.x >> 5;
    #pragma unroll
    for (int r = 0; r < 32; r += 8)
        tile[ly + r][lx] = bi[(size_t)(tr + ly + r) * C + tc + lx];
    __syncthreads();
    #pragma unroll
    for (int r = 0; r < 32; r += 8)
        bo[(size_t)(tc + ly + r) * R + tr + lx] = __float2bfloat16(tile[lx][ly + r]);
}

// One stage: act[128][256] (LDS, swizzled) <- f(act @ W + bias).
// Operand-swapped MFMA: D = W^T (A-op, global L2-hot) x act^T (B-op, LDS).
// Wave w owns weight-col strip [w*64,+64) (4 m-tiles) x all 128 rows (8 n-t).
// Weight matrix read from global exactly once per block per stage.
// Prefetch depth 2 on weight frags (covers ~L2 hit latency).
__device__ void run_stage(__hip_bfloat16* act,
                          const __hip_bfloat16* __restrict__ Wt,   // [n][k] row-major
                          const float* __restrict__ bias,
                          bool do_gelu, int wave, int lane)
{
    const int lr = lane & 15;
    const int q  = lane >> 4;
    const int wc = wave << 6;           // weight-col strip base

    const __hip_bfloat16* wrow[4];
    #pragma unroll
    for (int mt = 0; mt < 4; ++mt)
        wrow[mt] = Wt + (size_t)(wc + (mt << 4) + lr) * 256 + (q << 3);

    f32x4_t acc[4][8];
    #pragma unroll
    for (int mt = 0; mt < 4; ++mt)
        #pragma unroll
        for (int nt = 0; nt < 8; ++nt)
            acc[mt][nt] = (f32x4_t){0.f, 0.f, 0.f, 0.f};

    // prefetch A-frags (weights) for kc=0,1
    bf16x8_t a0[4], a1[4];
    #pragma unroll
    for (int mt = 0; mt < 4; ++mt) a0[mt] = *(const bf16x8_t*)(wrow[mt]);
    #pragma unroll
    for (int mt = 0; mt < 4; ++mt) a1[mt] = *(const bf16x8_t*)(wrow[mt] + 32);

    #pragma unroll 1
    for (int kc = 0; kc < 8; ++kc) {
        const int kof = (kc << 5) + (q << 3);
        bf16x8_t an[4];
        if (kc < 6) {
            #pragma unroll
            for (int mt = 0; mt < 4; ++mt)
                an[mt] = *(const bf16x8_t*)(wrow[mt] + ((kc + 2) << 5));
        }
        bf16x8_t b[8];
        #pragma unroll
        for (int nt = 0; nt < 8; ++nt)
            b[nt] = *(const bf16x8_t*)(act + act_addr((nt << 4) + lr, kof));
        #pragma unroll
        for (int mt = 0; mt < 4; ++mt)
            #pragma unroll
            for (int nt = 0; nt < 8; ++nt)
                acc[mt][nt] = __builtin_amdgcn_mfma_f32_16x16x32_bf16(a0[mt], b[nt], acc[mt][nt], 0, 0, 0);
        #pragma unroll
        for (int mt = 0; mt < 4; ++mt) { a0[mt] = a1[mt]; a1[mt] = an[mt]; }
    }

    __syncthreads();   // all waves done reading act before overwrite
    #pragma unroll
    for (int mt = 0; mt < 4; ++mt) {
        const int nbase = wc + (mt << 4) + (q << 2);
        const float4 bv = *(const float4*)(bias + nbase);
        #pragma unroll
        for (int nt = 0; nt < 8; ++nt) {
            const int row = (nt << 4) + lr;
            union { __hip_bfloat16 h[4]; uint64_t u; } o;
            #pragma unroll
            for (int r = 0; r < 4; ++r) {
                float v = acc[mt][nt][r] + ((const float*)&bv)[r];
                if (do_gelu) v = gelu_fast(v);
                o.h[r] = __float2bfloat16(v);
            }
            *(uint64_t*)(act + act_addr(row, nbase)) = o.u;
        }
    }
    __syncthreads();
}

__launch_bounds__(256, 2)
__global__ void chain_kernel(const __hip_bfloat16* __restrict__ xb,
                             const __hip_bfloat16* __restrict__ Tw1t,
                             const float* __restrict__ Tb1,
                             const __hip_bfloat16* __restrict__ Tw2t,
                             const float* __restrict__ Tb2,
                             const __hip_bfloat16* __restrict__ Ew1t,
                             const float* __restrict__ Eb1,
                             const __hip_bfloat16* __restrict__ Ew2t,
                             const float* __restrict__ Eb2,
                             uint8_t* __restrict__ zbuf,   // fp8 e4m3, [row][slot][256]
                             int b0)
{
    __shared__ __align__(16) __hip_bfloat16 act[128 * 256];   // 64 KB
    const int tid  = threadIdx.x;
    const int wave = tid >> 6, lane = tid & 63;
    const int slot = blockIdx.y;
    const int tile = blockIdx.x;

    // stage x tile (128 rows) into LDS
    #pragma unroll
    for (int i = 0; i < 16; ++i) {
        int lin = i * 256 + tid;
        int r = lin >> 5, g = lin & 31;
        bf16x8_t v = *(const bf16x8_t*)(xb + (size_t)(b0 + tile * 128 + r) * 256 + g * 8);
        *(bf16x8_t*)(act + act_addr(r, g * 8)) = v;
    }
    __syncthreads();

    if (slot < KTR) {
        run_stage(act, Tw1t + (size_t)slot * 65536, Tb1 + slot * 256, true,  wave, lane);
        run_stage(act, Tw2t + (size_t)slot * 65536, Tb2 + slot * 256, false, wave, lane);
    }
    run_stage(act, Ew1t, Eb1, true,  wave, lane);
    run_stage(act, Ew2t, Eb2, false, wave, lane);

    // copy-out z tile as fp8 e4m3 (HW cvt, OCP on gfx950): [row][slot][256]
    #pragma unroll
    for (int i = 0; i < 16; ++i) {
        int lin = i * 256 + tid;
        int r = lin >> 5, g = lin & 31;
        bf16x8_t v = *(const bf16x8_t*)(act + act_addr(r, g * 8));
        float f[8];
        #pragma unroll
        for (int e = 0; e < 8; ++e) {
            union { short s; __hip_bfloat16 h; } cv; cv.s = v[e];
            f[e] = __bfloat162float(cv.h);
        }
        int w0 = 0, w1 = 0;
        w0 = __builtin_amdgcn_cvt_pk_fp8_f32(f[0], f[1], w0, false);
        w0 = __builtin_amdgcn_cvt_pk_fp8_f32(f[2], f[3], w0, true);
        w1 = __builtin_amdgcn_cvt_pk_fp8_f32(f[4], f[5], w1, false);
        w1 = __builtin_amdgcn_cvt_pk_fp8_f32(f[6], f[7], w1, true);
        uint8_t* dst = zbuf + ((size_t)(tile * 128 + r) * NSLOT + slot) * 256 + g * 8;
        uint2 o; o.x = (uint32_t)w0; o.y = (uint32_t)w1;
        *(uint2*)dst = o;
    }
}

// Per row: G = Z Z^T (12x12 over H=256) via fp8 mfma(v,v,acc), A==B frag
// (Gram trick is k-permutation invariant). 8 rows/block, 2 per wave,
// ONE block barrier; Gram + tail wave-local. zbuf is L3-resident (201 MB).
__launch_bounds__(256, 4)
__global__ void reduce_kernel(const uint8_t* __restrict__ zbuf,
                              float* __restrict__ out, int b0)
{
    __shared__ __align__(16) uint8_t zs[8 * NSLOT * 256];   // 24 KB
    __shared__ float Gw[4][16][17];
    const int tid  = threadIdx.x;
    const int wave = tid >> 6, lane = tid & 63;
    const int lr = lane & 15, q = lane >> 4;

    const size_t base = (size_t)blockIdx.x * (8 * NSLOT * 256);
    #pragma unroll
    for (int i = 0; i < 6; ++i) {
        int lin = (i * 256 + tid) * 16;
        uint4 v = *(const uint4*)(zbuf + base + lin);
        *(uint4*)(zs + z8_addr(lin >> 8, lin & 255)) = v;
    }
    __syncthreads();   // the only block-wide barrier

    const int zslot = lr < NSLOT ? lr : NSLOT - 1;   // lanes 12-15 dup slot 11

    #pragma unroll 1
    for (int rr = 0; rr < 2; ++rr) {
        const int rs0 = (wave * 2 + rr) * NSLOT;
        f32x4_t acc = (f32x4_t){0.f, 0.f, 0.f, 0.f};
        #pragma unroll
        for (int kc = 0; kc < 8; ++kc) {
            const int off = kc * 32 + q * 8;
            long v = *(const long*)(zs + z8_addr(rs0 + zslot, off));
            acc = __builtin_amdgcn_mfma_f32_16x16x32_fp8_fp8(v, v, acc, 0, 0, 0);
        }
        #pragma unroll
        for (int r = 0; r < 4; ++r)
            Gw[wave][(q << 2) + r][lr] = acc[r];
        // wave-local RAW on Gw: lgkmcnt orders it; no block barrier needed
        float term = 0.f;
        if (lane < 11) {
            const int k = lane;
            float n[NSLOT];
            #pragma unroll
            for (int l = 0; l < NSLOT; ++l) n[l] = sqrtf(Gw[wave][l][l]);
            const float nk = n[k];
            float neg = 0.f;
            #pragma unroll
            for (int l = 0; l < KTR; ++l)
                if (l != k)
                    neg += __expf(Gw[wave][l][k] / fmaxf(n[l] * nk, 1e-8f));
            float cz = Gw[wave][KTR][k] / fmaxf(n[KTR] * nk, 1e-8f);
            term = __logf(__expf(cz) + neg) - cz;
        }
        term += __shfl_xor(term, 1);
        term += __shfl_xor(term, 2);
        term += __shfl_xor(term, 4);
        term += __shfl_xor(term, 8);
        if (lane == 0) out[b0 + blockIdx.x * 8 + wave * 2 + rr] = term;
    }
}

extern "C" void kernel_launch(void* const* d_in, const int* in_sizes, int n_in,
                              void* d_out, int out_size, void* d_ws, size_t ws_size,
                              hipStream_t stream)
{
    const float* x   = (const float*)d_in[0];
    const float* Tw1 = (const float*)d_in[1];
    const float* Tb1 = (const float*)d_in[2];
    const float* Tw2 = (const float*)d_in[3];
    const float* Tb2 = (const float*)d_in[4];
    const float* Ew1 = (const float*)d_in[5];
    const float* Eb1 = (const float*)d_in[6];
    const float* Ew2 = (const float*)d_in[7];
    const float* Eb2 = (const float*)d_in[8];
    float* out = (float*)d_out;

    char* ws = (char*)d_ws;
    const size_t off_xb  = 0;
    const size_t off_tw1 = off_xb  + (size_t)BTOT * 256 * 2;   // 32 MB
    const size_t off_tw2 = off_tw1 + (size_t)KTR * 65536 * 2;
    const size_t off_ew1 = off_tw2 + (size_t)KTR * 65536 * 2;
    const size_t off_ew2 = off_ew1 + (size_t)65536 * 2;
    const size_t off_z   = off_ew2 + (size_t)65536 * 2;

    __hip_bfloat16* xb   = (__hip_bfloat16*)(ws + off_xb);
    __hip_bfloat16* Tw1t = (__hip_bfloat16*)(ws + off_tw1);
    __hip_bfloat16* Tw2t = (__hip_bfloat16*)(ws + off_tw2);
    __hip_bfloat16* Ew1t = (__hip_bfloat16*)(ws + off_ew1);
    __hip_bfloat16* Ew2t = (__hip_bfloat16*)(ws + off_ew2);
    uint8_t*        zbuf = (uint8_t*)(ws + off_z);             // fp8: 201 MB < L3

    // single pass if scratch allows; chunk only as fallback
    long long zbytes = (long long)ws_size - (long long)off_z;
    long long rows_cap = zbytes > 0 ? zbytes / ((long long)NSLOT * 256) : 0;
    int chunk = (int)((rows_cap / 128) * 128);
    if (chunk > BTOT) chunk = BTOT;
    if (chunk < 128) chunk = 128;

    cast_x_kernel<<<dim3(BTOT * 256 / 1024), 256, 0, stream>>>(x, xb);
    transpose_cast_kernel<<<dim3(64, KTR), 256, 0, stream>>>(Tw1, Tw1t, 256, 256);
    transpose_cast_kernel<<<dim3(64, KTR), 256, 0, stream>>>(Tw2, Tw2t, 256, 256);
    transpose_cast_kernel<<<dim3(64, 1),   256, 0, stream>>>(Ew1, Ew1t, 256, 256);
    transpose_cast_kernel<<<dim3(64, 1),   256, 0, stream>>>(Ew2, Ew2t, 256, 256);

    for (int b0 = 0; b0 < BTOT; b0 += chunk) {
        int rows = (BTOT - b0 < chunk) ? (BTOT - b0) : chunk;
        chain_kernel<<<dim3(rows / 128, NSLOT), 256, 0, stream>>>(
            xb, Tw1t, Tb1, Tw2t, Tb2, Ew1t, Eb1, Ew2t, Eb2, zbuf, b0);
        reduce_kernel<<<dim3(rows / 8), 256, 0, stream>>>(zbuf, out, b0);
    }
}